// Round 4
// baseline (874.300 us; speedup 1.0000x reference)
//
#include <hip/hip_runtime.h>

#define NN 10000
#define EE 160000
#define DD 512
#define EDIM 128
#define LLAYERS 3
#define LN_EPS 1e-5f

typedef __attribute__((ext_vector_type(8))) short bf16x8;
typedef __attribute__((ext_vector_type(4))) float f32x4;
typedef __attribute__((ext_vector_type(4))) unsigned int u32x4;

__device__ __forceinline__ unsigned short f2b(float f) {
    union { float f; unsigned u; } v; v.f = f;
    unsigned r = (v.u + 0x7fffu + ((v.u >> 16) & 1u)) >> 16;
    return (unsigned short)r;
}
__device__ __forceinline__ float b2f(unsigned short s) {
    union { unsigned u; float f; } v; v.u = ((unsigned)s) << 16;
    return v.f;
}
__device__ __forceinline__ unsigned short f2h(float f) {
    _Float16 h = (_Float16)f;
    unsigned short u; __builtin_memcpy(&u, &h, 2);
    return u;
}
__device__ __forceinline__ float h2f(unsigned short u) {
    _Float16 h; __builtin_memcpy(&h, &u, 2);
    return (float)h;
}

// ---------------- CSR build: counting sort of edges by dst ----------------
__global__ __launch_bounds__(256) void hist_kernel(
    const int* __restrict__ dstv, int* __restrict__ deg)
{
    int e = blockIdx.x * 256 + threadIdx.x;
    if (e < EE) atomicAdd(&deg[dstv[e]], 1);
}

__global__ __launch_bounds__(256) void scan_kernel(
    const int* __restrict__ deg, int* __restrict__ base, int* __restrict__ cursor)
{
    __shared__ int sums[256];
    const int t = threadIdx.x;
    const int CH = 40;                       // 256*40 = 10240 >= NN
    int lo = t * CH;
    int hi = lo + CH; if (hi > NN) hi = NN;
    int s = 0;
    for (int i = lo; i < hi; i++) s += deg[i];
    sums[t] = s;
    __syncthreads();
    for (int off = 1; off < 256; off <<= 1) {
        int v = (t >= off) ? sums[t - off] : 0;
        __syncthreads();
        sums[t] += v;
        __syncthreads();
    }
    int run = (t == 0) ? 0 : sums[t - 1];
    for (int i = lo; i < hi; i++) {
        base[i] = run; cursor[i] = run;
        run += deg[i];
    }
}

__global__ __launch_bounds__(256) void scatter_kernel(
    const int* __restrict__ srcv, const int* __restrict__ dstv,
    int* __restrict__ cursor,
    int* __restrict__ ssrc, int* __restrict__ sdst, int* __restrict__ perm)
{
    int e = blockIdx.x * 256 + threadIdx.x;
    if (e < EE) {
        int d = dstv[e];
        int pos = atomicAdd(&cursor[d], 1);
        ssrc[pos] = srcv[e];
        sdst[pos] = d;
        perm[pos] = e;
    }
}

// ---------------- fp32 -> bf16 transpose (src[K][N] -> dst[N][K]) ----------------
__global__ __launch_bounds__(256) void transpose_bf16_kernel(
    const float* __restrict__ src, unsigned short* __restrict__ dst, int K, int N)
{
    __shared__ float t[32][33];
    const int x = threadIdx.x & 31;
    const int y = threadIdx.x >> 5;          // 0..7
    const int bn = blockIdx.x * 32;
    const int bk = blockIdx.y * 32;
    #pragma unroll
    for (int j = 0; j < 32; j += 8)
        t[y + j][x] = src[(size_t)(bk + y + j) * N + bn + x];
    __syncthreads();
    #pragma unroll
    for (int j = 0; j < 32; j += 8)
        dst[(size_t)(bn + y + j) * K + bk + x] = f2b(t[x][y + j]);
}

// ---------------- fp32 -> bf16 elementwise convert (4 elems/thread) ----------------
__global__ __launch_bounds__(256) void cvt_bf16_kernel(
    const float* __restrict__ src, unsigned short* __restrict__ dst)
{
    int i = blockIdx.x * 256 + threadIdx.x;
    float4 v = ((const float4*)src)[i];
    uint2 o;
    o.x = (unsigned)f2b(v.x) | ((unsigned)f2b(v.y) << 16);
    o.y = (unsigned)f2b(v.z) | ((unsigned)f2b(v.w) << 16);
    ((uint2*)dst)[i] = o;
}

// ---------------- perm-gather edge_attr fp32 -> bf16, sorted order ----------------
// thread handles 4 cols of one sorted row. grid = cnt*32/256 = cnt/8 (cnt % 128 == 0).
__global__ __launch_bounds__(256) void gather_cvt_kernel(
    const float* __restrict__ ea, const int* __restrict__ perm,
    unsigned short* __restrict__ out, int elo)
{
    int i = blockIdx.x * 256 + threadIdx.x;
    int r = i >> 5, c4 = (i & 31) * 4;
    const float* p = ea + (size_t)perm[elo + r] * EDIM + c4;
    float4 v = *(const float4*)p;
    uint2 o;
    o.x = (unsigned)f2b(v.x) | ((unsigned)f2b(v.y) << 16);
    o.y = (unsigned)f2b(v.z) | ((unsigned)f2b(v.w) << 16);
    *(uint2*)&out[(size_t)r * EDIM + c4] = o;
}

// ---------------- unified tile GEMM ----------------
// C[M,512] = act(A[M,KDIM] @ W + bias). Block: 128 rows x 128 cols.
// 4 waves: wave w -> row-half (w&1)*64, col-half (w>>1)*64; acc 4x4 frags.
// A staged in LDS per 128-k-chunk (coalesced uint4); B (WT [512 n][KDIM k],
// <=512 KB) read directly from global (L2-resident).
// Epilogue (OUT!=2): scatter fragment values into LDS (aliases sA, dead after
// MFMA) then write coalesced 16B rows at col base c0; OUT==1 (fp16 msg) uses
// nontemporal stores so the 164 MB stream doesn't evict ea/h from L3.
// OUT: 0 = bf16, 1 = fp16 nontemporal, 2 = f32 scalar (final layer).
#define MEP 136    // pitch: 128+8 shorts, 16B-aligned rows
template <int KDIM, bool RELU, int OUT>
__global__ __launch_bounds__(256) void tile_gemm(
    const unsigned short* __restrict__ A,    // [M][KDIM] bf16
    const unsigned short* __restrict__ WT,   // [512 n][KDIM k] bf16
    const float* __restrict__ bias,          // [512] fp32
    void* __restrict__ Cout, int M)
{
    __shared__ unsigned short sA[128 * MEP]; // 34.8 KB (reused as sOut)

    const int tid  = threadIdx.x;
    const int c0   = blockIdx.x * 128;       // col slab (fastest -> A-tile shared)
    const int m0   = blockIdx.y * 128;       // row tile
    const int w    = tid >> 6;
    const int lane = tid & 63;
    const int quad = lane >> 4;
    const int l16  = lane & 15;
    const int mh   = (w & 1) * 64;
    const int nsl  = (w >> 1) * 64;

    f32x4 acc[4][4];
    #pragma unroll
    for (int mr = 0; mr < 4; mr++)
        #pragma unroll
        for (int nb = 0; nb < 4; nb++)
            acc[mr][nb] = (f32x4){0.f, 0.f, 0.f, 0.f};

    for (int kc = 0; kc < KDIM; kc += 128) {
        if (kc) __syncthreads();
        for (int i = tid; i < 128 * 16; i += 256) {
            int r = i >> 4, seg = i & 15;
            int gm = m0 + r;
            u32x4 v = (u32x4){0u, 0u, 0u, 0u};
            if (gm < M)
                v = *(const u32x4*)&A[(size_t)gm * KDIM + kc + seg * 8];
            *(u32x4*)&sA[r * MEP + seg * 8] = v;
        }
        __syncthreads();
        #pragma unroll
        for (int ks = 0; ks < 4; ks++) {
            const int ko = ks * 32 + quad * 8;
            bf16x8 a[4];
            #pragma unroll
            for (int mr = 0; mr < 4; mr++)
                a[mr] = *(const bf16x8*)&sA[(mh + mr * 16 + l16) * MEP + ko];
            bf16x8 b[4];
            #pragma unroll
            for (int nb = 0; nb < 4; nb++)
                b[nb] = *(const bf16x8*)&WT[(size_t)(c0 + nsl + nb * 16 + l16) * KDIM + kc + ko];
            #pragma unroll
            for (int mr = 0; mr < 4; mr++)
                #pragma unroll
                for (int nb = 0; nb < 4; nb++)
                    acc[mr][nb] = __builtin_amdgcn_mfma_f32_16x16x32_bf16(a[mr], b[nb], acc[mr][nb], 0, 0, 0);
        }
    }

    if (OUT == 2) {
        float* Co = (float*)Cout;
        #pragma unroll
        for (int mr = 0; mr < 4; mr++) {
            const int rb = m0 + mh + mr * 16 + quad * 4;
            #pragma unroll
            for (int nb = 0; nb < 4; nb++) {
                const int c = c0 + nsl + nb * 16 + l16;
                const float bv = bias[c];
                const f32x4 v = acc[mr][nb];
                #pragma unroll
                for (int reg = 0; reg < 4; reg++) {
                    int gm = rb + reg;
                    if (gm < M) {
                        float val = v[reg] + bv;
                        if (RELU) val = fmaxf(val, 0.f);
                        Co[(size_t)gm * DD + c] = val;
                    }
                }
            }
        }
    } else {
        __syncthreads();                      // all sA reads done -> reuse as sOut
        #pragma unroll
        for (int mr = 0; mr < 4; mr++) {
            const int lr = mh + mr * 16 + quad * 4;
            #pragma unroll
            for (int nb = 0; nb < 4; nb++) {
                const int lc = nsl + nb * 16 + l16;
                const float bv = bias[c0 + lc];
                const f32x4 v = acc[mr][nb];
                #pragma unroll
                for (int reg = 0; reg < 4; reg++) {
                    float val = v[reg] + bv;
                    if (RELU) val = fmaxf(val, 0.f);
                    sA[(lr + reg) * MEP + lc] = (OUT == 0) ? f2b(val) : f2h(val);
                }
            }
        }
        __syncthreads();
        unsigned short* Co = (unsigned short*)Cout;
        for (int i = tid; i < 128 * 16; i += 256) {
            int r = i >> 4, seg = i & 15;
            int gm = m0 + r;
            if (gm < M) {
                u32x4 v = *(const u32x4*)&sA[r * MEP + seg * 8];
                if (OUT == 1)
                    __builtin_nontemporal_store(v, (u32x4*)&Co[(size_t)gm * DD + c0 + seg * 8]);
                else
                    *(u32x4*)&Co[(size_t)gm * DD + c0 + seg * 8] = v;
            }
        }
    }
}

// ---------------- CSR per-dst aggregation: zero atomics, zero LDS -----------------
// One block per dst row; thread t owns cols (2t, 2t+1). 4-wide manual unroll
// keeps 8 loads in flight (runtime trip count defeats compiler pipelining).
// msg reads nontemporal: 164 MB stream must not evict the 10 MB h table.
__global__ __launch_bounds__(256) void agg_kernel(
    const unsigned short* __restrict__ h_bf,
    const unsigned short* __restrict__ msg,   // fp16 bits, chunk-local rows
    const int* __restrict__ ssrc,
    const int* __restrict__ basep,
    const int* __restrict__ degp,
    const float* __restrict__ epsp,
    float* __restrict__ aggp,
    unsigned short* __restrict__ aprime,
    int elo, int ehi, int first, int last)
{
    const int d  = blockIdx.x;
    const int b0 = basep[d];
    const int b1 = b0 + degp[d];
    int lo = b0 > elo ? b0 : elo;
    int hi = b1 < ehi ? b1 : ehi;
    if (!first && !last && lo >= hi) return;   // middle chunk, nothing to add

    const int t  = threadIdx.x;
    const int c2 = t * 2;

    float a0 = 0.f, a1 = 0.f;
    if (!first) {
        float2 pv = *(const float2*)&aggp[(size_t)d * DD + c2];
        a0 = pv.x; a1 = pv.y;
    }
    int p = lo;
    for (; p + 4 <= hi; p += 4) {
        const int s0 = ssrc[p],     s1 = ssrc[p + 1];
        const int s2 = ssrc[p + 2], s3 = ssrc[p + 3];
        unsigned m0v = __builtin_nontemporal_load((const unsigned*)&msg[(size_t)(p     - elo) * DD + c2]);
        unsigned m1v = __builtin_nontemporal_load((const unsigned*)&msg[(size_t)(p + 1 - elo) * DD + c2]);
        unsigned m2v = __builtin_nontemporal_load((const unsigned*)&msg[(size_t)(p + 2 - elo) * DD + c2]);
        unsigned m3v = __builtin_nontemporal_load((const unsigned*)&msg[(size_t)(p + 3 - elo) * DD + c2]);
        unsigned h0v = *(const unsigned*)&h_bf[(size_t)s0 * DD + c2];
        unsigned h1v = *(const unsigned*)&h_bf[(size_t)s1 * DD + c2];
        unsigned h2v = *(const unsigned*)&h_bf[(size_t)s2 * DD + c2];
        unsigned h3v = *(const unsigned*)&h_bf[(size_t)s3 * DD + c2];
        a0 += fmaxf(h2f((unsigned short)(m0v & 0xffffu)) + b2f((unsigned short)(h0v & 0xffffu)), 0.f);
        a1 += fmaxf(h2f((unsigned short)(m0v >> 16))     + b2f((unsigned short)(h0v >> 16)),     0.f);
        a0 += fmaxf(h2f((unsigned short)(m1v & 0xffffu)) + b2f((unsigned short)(h1v & 0xffffu)), 0.f);
        a1 += fmaxf(h2f((unsigned short)(m1v >> 16))     + b2f((unsigned short)(h1v >> 16)),     0.f);
        a0 += fmaxf(h2f((unsigned short)(m2v & 0xffffu)) + b2f((unsigned short)(h2v & 0xffffu)), 0.f);
        a1 += fmaxf(h2f((unsigned short)(m2v >> 16))     + b2f((unsigned short)(h2v >> 16)),     0.f);
        a0 += fmaxf(h2f((unsigned short)(m3v & 0xffffu)) + b2f((unsigned short)(h3v & 0xffffu)), 0.f);
        a1 += fmaxf(h2f((unsigned short)(m3v >> 16))     + b2f((unsigned short)(h3v >> 16)),     0.f);
    }
    for (; p < hi; p++) {
        const int s = ssrc[p];
        unsigned mv = __builtin_nontemporal_load((const unsigned*)&msg[(size_t)(p - elo) * DD + c2]);
        unsigned hv = *(const unsigned*)&h_bf[(size_t)s * DD + c2];
        a0 += fmaxf(h2f((unsigned short)(mv & 0xffffu)) + b2f((unsigned short)(hv & 0xffffu)), 0.f);
        a1 += fmaxf(h2f((unsigned short)(mv >> 16))     + b2f((unsigned short)(hv >> 16)),     0.f);
    }
    if (last) {
        const float es = 1.0f + epsp[0];
        unsigned hv = *(const unsigned*)&h_bf[(size_t)d * DD + c2];
        unsigned o = (unsigned)f2b(es * b2f((unsigned short)(hv & 0xffffu)) + a0)
                   | ((unsigned)f2b(es * b2f((unsigned short)(hv >> 16))    + a1) << 16);
        *(unsigned*)&aprime[(size_t)d * DD + c2] = o;
    } else {
        *(float2*)&aggp[(size_t)d * DD + c2] = make_float2(a0, a1);
    }
}

// ---------------- fused ReLU + LayerNorm (bf16 in/out, fp32 stats) ----------------
__global__ __launch_bounds__(256) void relu_ln_kernel(
    const unsigned short* __restrict__ g2,
    const float* __restrict__ gamma,
    const float* __restrict__ beta,
    unsigned short* __restrict__ hout)
{
    __shared__ float ss[4], ssq[4];
    const int row = blockIdx.x;
    const int tid = threadIdx.x;
    const unsigned short* gr = g2 + (size_t)row * DD;

    float v0 = fmaxf(b2f(gr[tid]), 0.f);
    float v1 = fmaxf(b2f(gr[tid + 256]), 0.f);
    float s  = v0 + v1;
    float sq = v0 * v0 + v1 * v1;
    #pragma unroll
    for (int off = 32; off > 0; off >>= 1) {
        s  += __shfl_down(s, off);
        sq += __shfl_down(sq, off);
    }
    const int wave = tid >> 6;
    const int lane = tid & 63;
    if (lane == 0) { ss[wave] = s; ssq[wave] = sq; }
    __syncthreads();
    if (tid == 0) {
        float S  = ss[0] + ss[1] + ss[2] + ss[3];
        float SQ = ssq[0] + ssq[1] + ssq[2] + ssq[3];
        float mu = S * (1.f / 512.f);
        float var = SQ * (1.f / 512.f) - mu * mu;
        ss[0]  = mu;
        ssq[0] = rsqrtf(var + LN_EPS);
    }
    __syncthreads();
    float mu = ss[0], rstd = ssq[0];
    hout[(size_t)row * DD + tid] =
        f2b((v0 - mu) * rstd * gamma[tid] + beta[tid]);
    hout[(size_t)row * DD + tid + 256] =
        f2b((v1 - mu) * rstd * gamma[tid + 256] + beta[tid + 256]);
}

extern "C" void kernel_launch(void* const* d_in, const int* in_sizes, int n_in,
                              void* d_out, int out_size, void* d_ws, size_t ws_size,
                              hipStream_t stream)
{
    (void)in_sizes; (void)n_in; (void)out_size;

    const float* x          = (const float*)d_in[0];
    const int*   edge_index = (const int*)d_in[1];   // int32 per harness contract
    const float* edge_attr  = (const float*)d_in[2];
    const float* We         = (const float*)d_in[3];
    const float* be         = (const float*)d_in[4];
    const float* eps        = (const float*)d_in[5];
    const float* W1         = (const float*)d_in[6];
    const float* b1         = (const float*)d_in[7];
    const float* W2         = (const float*)d_in[8];
    const float* b2         = (const float*)d_in[9];
    const float* gamma      = (const float*)d_in[10];
    const float* beta       = (const float*)d_in[11];
    const float* Wf         = (const float*)d_in[12];
    const float* bf         = (const float*)d_in[13];

    // ---- workspace layout ----
    unsigned short* h_bf   = (unsigned short*)d_ws;                 // [N*512] bf16
    unsigned short* aprime = h_bf + (size_t)NN * DD;                // [N*512] bf16
    unsigned short* t1     = aprime + (size_t)NN * DD;              // [N*512] bf16
    unsigned short* t2     = t1 + (size_t)NN * DD;                  // [N*512] bf16
    unsigned short* WeT    = t2 + (size_t)NN * DD;                  // [3][512][128]
    unsigned short* W1T    = WeT + (size_t)LLAYERS * DD * EDIM;     // [3][512][512]
    unsigned short* W2T    = W1T + (size_t)LLAYERS * DD * DD;
    unsigned short* WfT    = W2T + (size_t)LLAYERS * DD * DD;       // [512][512]
    int* deg    = (int*)(WfT + (size_t)DD * DD);
    int* basep  = deg + NN;
    int* cursor = basep + NN;
    int* ssrc   = cursor + NN;
    int* sdst   = ssrc + EE;
    int* perm   = sdst + EE;
    float* aggp = (float*)(perm + EE);                              // [N*512] fp32 partials
    unsigned short* ea_hf = (unsigned short*)(aggp + (size_t)NN * DD);

    // dynamic msg/ea capacity from remaining workspace
    size_t used = (size_t)((unsigned char*)ea_hf - (unsigned char*)d_ws);
    size_t rem  = ws_size > used ? ws_size - used : 0;
    const size_t EA_FULL  = (size_t)EE * EDIM * 2;   // 41.0 MB
    const size_t MSG_FULL = (size_t)EE * DD * 2;     // 163.8 MB
    int ea_full; long long capE;
    if (rem >= EA_FULL + MSG_FULL) {
        ea_full = 1; capE = EE;                      // single chunk (expected path)
    } else if (rem >= EA_FULL + (size_t)32 * 1024 * 1024) {
        ea_full = 1;
        capE = (long long)((rem - EA_FULL) / ((size_t)DD * 2)) & ~127LL;
    } else {
        ea_full = 0;
        capE = (long long)(rem / ((size_t)(EDIM + DD) * 2)) & ~127LL;
        if (capE < 128) capE = 128;
    }
    if (capE > EE) capE = EE;
    unsigned short* msg = ea_hf + (ea_full ? (size_t)EE * EDIM : (size_t)capE * EDIM);

    const int* srcv = edge_index;
    const int* dstv = edge_index + EE;

    // ---- prepass: sort, converts, transposes ----
    hipMemsetAsync(deg, 0, NN * sizeof(int), stream);
    hist_kernel<<<dim3((EE + 255) / 256), 256, 0, stream>>>(dstv, deg);
    scan_kernel<<<dim3(1), 256, 0, stream>>>(deg, basep, cursor);
    scatter_kernel<<<dim3((EE + 255) / 256), 256, 0, stream>>>(
        srcv, dstv, cursor, ssrc, sdst, perm);

    cvt_bf16_kernel<<<dim3(NN * DD / 4 / 256), 256, 0, stream>>>(x, h_bf);
    for (int l = 0; l < LLAYERS; l++) {
        transpose_bf16_kernel<<<dim3(DD / 32, EDIM / 32), 256, 0, stream>>>(
            We + (size_t)l * EDIM * DD, WeT + (size_t)l * DD * EDIM, EDIM, DD);
        transpose_bf16_kernel<<<dim3(DD / 32, DD / 32), 256, 0, stream>>>(
            W1 + (size_t)l * DD * DD, W1T + (size_t)l * DD * DD, DD, DD);
        transpose_bf16_kernel<<<dim3(DD / 32, DD / 32), 256, 0, stream>>>(
            W2 + (size_t)l * DD * DD, W2T + (size_t)l * DD * DD, DD, DD);
    }
    transpose_bf16_kernel<<<dim3(DD / 32, DD / 32), 256, 0, stream>>>(Wf, WfT, DD, DD);

    if (ea_full)
        gather_cvt_kernel<<<dim3(EE / 8), 256, 0, stream>>>(edge_attr, perm, ea_hf, 0);

    dim3 ggrid(DD / 128, (NN + 127) / 128);   // (4 col slabs, 79 row tiles)

    const int nch = (int)((EE + capE - 1) / capE);
    for (int l = 0; l < LLAYERS; l++) {
        for (int c = 0; c < nch; c++) {
            const int elo = (int)((long long)c * capE);
            const int cnt = (EE - elo < capE) ? (EE - elo) : (int)capE;
            if (!ea_full)
                gather_cvt_kernel<<<dim3(cnt / 8), 256, 0, stream>>>(edge_attr, perm, ea_hf, elo);
            const unsigned short* Ab = ea_full ? ea_hf + (size_t)elo * EDIM : ea_hf;
            tile_gemm<EDIM, false, 1><<<dim3(4, cnt / 128), 256, 0, stream>>>(
                Ab, WeT + (size_t)l * DD * EDIM, be + (size_t)l * DD, msg, cnt);
            agg_kernel<<<dim3(NN), 256, 0, stream>>>(
                h_bf, msg, ssrc, basep, deg, eps + l, aggp, aprime,
                elo, elo + cnt, c == 0 ? 1 : 0, c == nch - 1 ? 1 : 0);
        }
        // gemm1: relu(aprime @ W1 + b1) -> t1 (bf16)
        tile_gemm<DD, true, 0><<<ggrid, 256, 0, stream>>>(
            aprime, W1T + (size_t)l * DD * DD, b1 + (size_t)l * DD, t1, NN);
        // gemm2: t1 @ W2 + b2 -> t2 (bf16)
        tile_gemm<DD, false, 0><<<ggrid, 256, 0, stream>>>(
            t1, W2T + (size_t)l * DD * DD, b2 + (size_t)l * DD, t2, NN);
        relu_ln_kernel<<<dim3(NN), 256, 0, stream>>>(
            t2, gamma + (size_t)l * DD, beta + (size_t)l * DD, h_bf);
    }
    tile_gemm<DD, false, 2><<<ggrid, 256, 0, stream>>>(h_bf, WfT, bf, d_out, NN);
}